// Round 9
// baseline (223.435 us; speedup 1.0000x reference)
//
#include <hip/hip_runtime.h>
#include <cstdint>

#define Bn 64
#define Ln 512
#define Hn 768
#define Tn 16
#define Cn 8      // chunks over L
#define Sn 64     // chunk length
#define Kn 4      // K-split for GEMM
#define Kc 192    // K-slice per GEMM block (768/4)
#define Mrows (Bn*Ln)   // 32768
#define LOG16 2.7725887222397812f

// ---------------- K_A: partial GEMM, split-K, W-in-LDS + register prefetch ----------
// r8 post-mortem: launch_bounds(256) pinned VGPR<=64 -> compiler SPILLED pv[4] to
// scratch every chunk (WRITE_SIZE 85MB = 1024blk x 256thr x 64B x 5 iters).  Fix:
// __launch_bounds__(256,4) — grid gives exactly 4 waves/SIMD, so raising the VGPR
// cap to 128 costs nothing and lets pv live in registers.  Prefetch then hides
// chunk cc+1's HBM latency under chunk cc's 512 FMA cycles as intended.
// Staging map, k-order (kb+cc*32, j asc, xyzw), store path lineage-exact
// -> partial/em BIT-IDENTICAL -> tags unchanged.
__global__ __launch_bounds__(256, 4) void k_gemm_part(
    const float* __restrict__ hs, const float* __restrict__ W,
    float* __restrict__ partial, float* __restrict__ lossws) {
  int bx = blockIdx.x;
  int tid = threadIdx.x;
  if (bx == 0 && tid == 0) {               // zero loss accumulator + ticket each iter
    lossws[0] = 0.f;
    ((int*)lossws)[1] = 0;
  }
  int rt = bx >> 2, s = bx & 3;
  int r0 = rt * 128, kb = s * Kc;
  int row = (tid & 63) + ((tid >> 7) << 6);   // waves 0,1 -> rows 0-63; waves 2,3 -> 64-127
  int t0 = ((tid >> 6) & 1) * 8;              // wave-uniform t-half
  __shared__ float alds[128 * 36];            // 18,432 B (stride 36: 0 conflicts measured)
  __shared__ float wlds[16 * 192];            // 12,288 B: W slice, broadcast-read
  float acc[8] = {0.f};
  // stage W slice once (768 float4, 3/thread, 16B runs per t-row)
  for (int idx = tid; idx < 768; idx += 256) {
    int t = idx / 48, jj = idx - t * 48;
    *(float4*)&wlds[t * 192 + jj * 4] = *(const float4*)(W + (size_t)t * Hn + kb + jj * 4);
  }
  // this thread's 4 staging slots (lineage map: f=it*256+tid, r=f>>3, j=f&7)
  int sr[4], sj[4];
#pragma unroll
  for (int it = 0; it < 4; ++it) { int f = it * 256 + tid; sr[it] = f >> 3; sj[it] = f & 7; }
  float4 pv[4];                               // register prefetch buffer (next chunk)
#pragma unroll
  for (int it = 0; it < 4; ++it)
    pv[it] = *(const float4*)(hs + (size_t)(r0 + sr[it]) * Hn + kb + sj[it] * 4);  // chunk 0
#pragma unroll 1
  for (int cc = 0; cc < 6; ++cc) {            // 6 sub-chunks of 32 K-floats
    int k0 = kb + cc * 32;
#pragma unroll
    for (int it = 0; it < 4; ++it)            // commit prefetched regs to LDS
      *(float4*)&alds[sr[it] * 36 + sj[it] * 4] = pv[it];
    __syncthreads();                          // covers W staging at cc=0 too
    if (cc < 5) {                             // issue next chunk's loads under the FMAs
#pragma unroll
      for (int it = 0; it < 4; ++it)
        pv[it] = *(const float4*)(hs + (size_t)(r0 + sr[it]) * Hn + (k0 + 32) + sj[it] * 4);
    }
#pragma unroll
    for (int j = 0; j < 8; ++j) {             // EXACT lineage nest: j asc, xyzw
      float4 a = *(const float4*)&alds[row * 36 + j * 4];
#pragma unroll
      for (int tt = 0; tt < 8; ++tt) {
        float4 wv = *(const float4*)&wlds[(t0 + tt) * 192 + cc * 32 + j * 4];  // broadcast
        acc[tt] = fmaf(a.x, wv.x, fmaf(a.y, wv.y, fmaf(a.z, wv.z, fmaf(a.w, wv.w, acc[tt]))));
      }
    }
    __syncthreads();
  }
  float* dst = partial + ((size_t)s * Mrows + (r0 + row)) * Tn + t0;
  *(float4*)(dst + 0) = make_float4(acc[0], acc[1], acc[2], acc[3]);
  *(float4*)(dst + 4) = make_float4(acc[4], acc[5], acc[6], acc[7]);
}

// ---------------- K_B: reduce+em, then ONE scan per block (r5 form, verbatim) -------
// blocks 0..511: reduce + denom scan (+em write); 512..1023: reduce + Viterbi.
// pbuf broadcast: 1 ds_write + 4 ds_read_b128 per step; serial chains keep exact
// order -> qmat/qv/hist bit-identical -> tags unchanged.
__global__ __launch_bounds__(256) void k_em_scan(
    const float* __restrict__ partial, const float* __restrict__ bias,
    const int* __restrict__ mask, const float* __restrict__ trans,
    float* __restrict__ em, float* __restrict__ qmat,
    float* __restrict__ qv, uint8_t* __restrict__ hist) {
  int half = blockIdx.x >> 9, bc = blockIdx.x & 511;
  int b = bc >> 3, c = bc & 7;
  int tid = threadIdx.x, i = tid >> 4, tp = tid & 15;
  int l0 = c * Sn;
  __shared__ float ems[Sn * Tn];
  __shared__ int msk[Sn];
  __shared__ float pbuf[256];            // per-group broadcast row (16 floats/group)
  __shared__ uint8_t hl[Tn * Sn * Tn];   // 16 KB (used by half 1 only)
  // phase 0: reduce partial -> em (bit-identical order: bias + s0..s3)
#pragma unroll
  for (int g = 0; g < 4; ++g) {
    int rl = (tid >> 4) + g * 16, t = tid & 15;
    int grow = bc * Sn + rl;
    float sum = bias[t];
#pragma unroll
    for (int s = 0; s < Kn; ++s) sum += partial[((size_t)s * Mrows + grow) * Tn + t];
    float mx = sum;
    mx = fmaxf(mx, __shfl_xor(mx, 1));
    mx = fmaxf(mx, __shfl_xor(mx, 2));
    mx = fmaxf(mx, __shfl_xor(mx, 4));
    mx = fmaxf(mx, __shfl_xor(mx, 8));
    float ev = sum - (mx + LOG16);
    ems[rl * Tn + t] = ev;
    if (half == 0) em[(size_t)grow * Tn + t] = ev;
  }
  if (tid < Sn) msk[tid] = mask[b * Ln + l0 + tid];
  __syncthreads();
  int lstart = (c == 0) ? 1 : l0;
  int gb = i << 4;                       // group base in pbuf (64B aligned)
  if (half == 0) {
    // denominator scan (linear space, renorm every 16); dot chain t=0..15 as lineage
    float etr[Tn];
#pragma unroll
    for (int t = 0; t < Tn; ++t) etr[t] = __expf(trans[t * Tn + tp]);
    float p = (tp == i) ? 1.f : 0.f;
    float logs = 0.f;
    for (int l = lstart; l < l0 + Sn; ++l) {
      pbuf[tid] = p;
      __builtin_amdgcn_sched_barrier(0);
      float4 q0 = *(const float4*)&pbuf[gb + 0];
      float4 q1 = *(const float4*)&pbuf[gb + 4];
      float4 q2 = *(const float4*)&pbuf[gb + 8];
      float4 q3 = *(const float4*)&pbuf[gb + 12];
      float cs = __expf(ems[(l - l0) * Tn + tp]);
      float dot = 0.f;
      dot = fmaf(q0.x, etr[0],  dot); dot = fmaf(q0.y, etr[1],  dot);
      dot = fmaf(q0.z, etr[2],  dot); dot = fmaf(q0.w, etr[3],  dot);
      dot = fmaf(q1.x, etr[4],  dot); dot = fmaf(q1.y, etr[5],  dot);
      dot = fmaf(q1.z, etr[6],  dot); dot = fmaf(q1.w, etr[7],  dot);
      dot = fmaf(q2.x, etr[8],  dot); dot = fmaf(q2.y, etr[9],  dot);
      dot = fmaf(q2.z, etr[10], dot); dot = fmaf(q2.w, etr[11], dot);
      dot = fmaf(q3.x, etr[12], dot); dot = fmaf(q3.y, etr[13], dot);
      dot = fmaf(q3.z, etr[14], dot); dot = fmaf(q3.w, etr[15], dot);
      float pn = dot * cs;
      p = msk[l - l0] ? pn : p;
      if ((l & 15) == 15) {
        float m = p;
        m = fmaxf(m, __shfl_xor(m, 1));
        m = fmaxf(m, __shfl_xor(m, 2));
        m = fmaxf(m, __shfl_xor(m, 4));
        m = fmaxf(m, __shfl_xor(m, 8));
        p /= m;
        logs += __logf(m);
      }
    }
    qmat[(((size_t)b * Cn + c) * Tn + i) * Tn + tp] = __logf(p) + logs;
  } else {
    // Viterbi scan (max-plus) + history; serial t=0..15, strict > keeps FIRST max
    float tcol[Tn];
#pragma unroll
    for (int t = 0; t < Tn; ++t) tcol[t] = trans[t * Tn + tp];
    float v = (tp == i) ? 0.f : -1e30f;
    for (int l = lstart; l < l0 + Sn; ++l) {
      pbuf[tid] = v;
      __builtin_amdgcn_sched_barrier(0);
      float4 q0 = *(const float4*)&pbuf[gb + 0];
      float4 q1 = *(const float4*)&pbuf[gb + 4];
      float4 q2 = *(const float4*)&pbuf[gb + 8];
      float4 q3 = *(const float4*)&pbuf[gb + 12];
      float best = -3.0e38f; int arg = 0;
#define VSTEP(val, t) { float cand = (val) + tcol[t]; bool g = cand > best; \
                        arg = g ? (t) : arg; best = g ? cand : best; }
      VSTEP(q0.x, 0)  VSTEP(q0.y, 1)  VSTEP(q0.z, 2)  VSTEP(q0.w, 3)
      VSTEP(q1.x, 4)  VSTEP(q1.y, 5)  VSTEP(q1.z, 6)  VSTEP(q1.w, 7)
      VSTEP(q2.x, 8)  VSTEP(q2.y, 9)  VSTEP(q2.z, 10) VSTEP(q2.w, 11)
      VSTEP(q3.x, 12) VSTEP(q3.y, 13) VSTEP(q3.z, 14) VSTEP(q3.w, 15)
#undef VSTEP
      v = best + ems[(l - l0) * Tn + tp];
      hl[(i * Sn + (l - l0)) * Tn + tp] = (uint8_t)arg;
    }
    qv[(((size_t)b * Cn + c) * Tn + i) * Tn + tp] = v;
    __syncthreads();
    const uint4* s4 = (const uint4*)hl;   // coalesced 16KB dump
    uint4* d4 = (uint4*)(hist + (size_t)bc * (Tn * Sn * Tn));
    for (int k = tid; k < (Tn * Sn * Tn) / 16; k += 256) d4[k] = s4[k];
  }
}

// ---------------- K_C: merged tail — folds now read from LDS-staged q-blocks --------
// The 8-iteration folds had L2-latency loads in their serial chains.  Each block
// preloads its 8KB qmat/qv block via 512 coalesced float4 loads issued at branch
// entry (latency hidden under the numer scan / one barrier), then folds from LDS.
// Same values -> bit-identical outputs.
__global__ __launch_bounds__(512) void k_tail(
    const float* __restrict__ qv, const float* __restrict__ em,
    const float* __restrict__ start, const float* __restrict__ endt,
    const uint8_t* __restrict__ hist, const int* __restrict__ labels,
    const int* __restrict__ mask, const float* __restrict__ trans,
    const float* __restrict__ qmat, float* __restrict__ lossws,
    float* __restrict__ loss_out, float* __restrict__ tags) {
  int bid = blockIdx.x, tid = threadIdx.x;
  __shared__ float qs[Cn * Tn * Tn];     // 8 KB staged fold matrix
  if (bid >= Bn) {
    // ---- numerator + denominator fold -> llh contribution for b = bid-64 ----
    int b = bid - Bn;
    // issue qmat preload first: 2048 floats = 512 float4, one per thread
    {
      float4 qv4 = *(((const float4*)qmat) + (size_t)b * 512 + tid);
      *(((float4*)qs) + tid) = qv4;
    }
    {
      int l = tid;                         // 512 threads = one l each
      int y = labels[b * Ln + l];
      int m = mask[b * Ln + l];
      float s;
      if (l == 0) s = start[y] + em[((size_t)b * Ln) * Tn + y];
      else s = m ? (trans[labels[b * Ln + l - 1] * Tn + y] + em[((size_t)b * Ln + l) * Tn + y]) : 0.f;
      int msum = m;
      for (int off = 32; off; off >>= 1) {
        s += __shfl_down(s, off);
        msum += __shfl_down(msum, off);
      }
      __shared__ float sw[8]; __shared__ int mw[8];
      __shared__ float snum;
      int wid = tid >> 6, ln = tid & 63;
      if (ln == 0) { sw[wid] = s; mw[wid] = msum; }
      __syncthreads();
      if (tid == 0) {
        float st = 0.f; int mt = 0;
        for (int wv = 0; wv < 8; ++wv) { st += sw[wv]; mt += mw[wv]; }
        snum = st + endt[labels[b * Ln + mt - 1]];
      }
      __syncthreads();                    // qs preload also complete by here
      if (tid < Tn) {                     // 16-lane log-space fold over LDS-staged qmat
        int k = tid;
        float p = start[k] + em[((size_t)b * Ln) * Tn + k];
        for (int c = 0; c < Cn; ++c) {
          float vals[Tn]; float mx = -3.0e38f;
#pragma unroll
          for (int i2 = 0; i2 < Tn; ++i2) {
            float cand = __shfl(p, i2, 16) + qs[c * 256 + i2 * 16 + k];
            vals[i2] = cand;
            mx = fmaxf(mx, cand);
          }
          float sm = 0.f;
#pragma unroll
          for (int i2 = 0; i2 < Tn; ++i2) sm += __expf(vals[i2] - mx);
          p = mx + __logf(sm);
        }
        float x = p + endt[k];
        float mx = x;
        mx = fmaxf(mx, __shfl_xor(mx, 1));
        mx = fmaxf(mx, __shfl_xor(mx, 2));
        mx = fmaxf(mx, __shfl_xor(mx, 4));
        mx = fmaxf(mx, __shfl_xor(mx, 8));
        float e = __expf(x - mx);
        e += __shfl_xor(e, 1);
        e += __shfl_xor(e, 2);
        e += __shfl_xor(e, 4);
        e += __shfl_xor(e, 8);
        float denom = mx + __logf(e);
        if (k == 0) {
          atomicAdd(&lossws[0], snum - denom);
          __threadfence();
          int ticket = atomicAdd((int*)lossws + 1, 1);
          if (ticket == Bn - 1) {         // last numer block finalizes loss
            __threadfence();
            float total = atomicAdd(&lossws[0], 0.f);
            loss_out[0] = -total * (1.0f / Bn);
          }
        }
      }
    }
    return;
  }
  // ---- Viterbi fold + parallel backtrack for b = bid ----
  int b = bid;
  __shared__ int Bs[Cn][Tn];
  __shared__ int bnd[Cn + 1];
  {
    float4 qv4 = *(((const float4*)qv) + (size_t)b * 512 + tid);  // stage qv block
    *(((float4*)qs) + tid) = qv4;
  }
  __syncthreads();
  if (tid < Tn) {
    int k = tid;
    float p = start[k] + em[((size_t)b * Ln) * Tn + k];
    for (int c = 0; c < Cn; ++c) {
      float best = -3.0e38f; int arg = 0;
#pragma unroll
      for (int i2 = 0; i2 < Tn; ++i2) {
        float cand = __shfl(p, i2, 16) + qs[c * 256 + i2 * 16 + k];
        bool g = cand > best;
        arg = g ? i2 : arg;
        best = g ? cand : best;
      }
      Bs[c][k] = arg;
      p = best;
    }
    float x = p + endt[k]; int idx = k;   // first-max argmax over k
#pragma unroll
    for (int d = 1; d < 16; d <<= 1) {
      float xo = __shfl_xor(x, d);
      int io = __shfl_xor(idx, d);
      bool take = (xo > x) || (xo == x && io < idx);
      x = take ? xo : x;
      idx = take ? io : idx;
    }
    if (k == 0) bnd[Cn] = idx;
  }
  __syncthreads();
  if (tid == 0) {
    int t = bnd[Cn];
    for (int c = Cn - 1; c >= 0; --c) { t = Bs[c][t]; bnd[c] = t; }
  }
  __syncthreads();
  int w = tid >> 6, lane = tid & 63;      // wave w backtracks chunk w
  int istar = bnd[w];
  int cur = bnd[w + 1];
  int l0 = w * Sn;
  const uint4* hp = (const uint4*)(hist + ((size_t)(b * Cn + w) * Tn + istar) * (Sn * Tn));
  uint4 hh = hp[lane];
  float mytag = (lane == 63) ? (float)cur : 0.f;
  for (int l = l0 + 63; l >= l0 + 1; --l) {
    int sl = l - l0;
    unsigned w0 = __shfl((int)hh.x, sl);
    unsigned w1 = __shfl((int)hh.y, sl);
    unsigned w2 = __shfl((int)hh.z, sl);
    unsigned w3 = __shfl((int)hh.w, sl);
    unsigned word = (cur < 8) ? ((cur < 4) ? w0 : w1) : ((cur < 12) ? w2 : w3);
    cur = (int)((word >> ((cur & 3) * 8)) & 0xff);
    if (lane == sl - 1) mytag = (float)cur;
  }
  tags[(size_t)b * Ln + l0 + lane] = mytag;
}

extern "C" void kernel_launch(void* const* d_in, const int* in_sizes, int n_in,
                              void* d_out, int out_size, void* d_ws, size_t ws_size,
                              hipStream_t stream) {
  const float* hs     = (const float*)d_in[0];
  const int*   mask   = (const int*)d_in[1];
  const int*   labels = (const int*)d_in[2];
  const float* W      = (const float*)d_in[3];
  const float* bias   = (const float*)d_in[4];
  const float* start  = (const float*)d_in[5];
  const float* endt   = (const float*)d_in[6];
  const float* trans  = (const float*)d_in[7];
  float* out = (float*)d_out;

  // Workspace (~19.9 MB, NO aliasing — partial & hist are concurrently live in K_B):
  //   em      @ 0          : 2,097,152
  //   qmat    @ 2,097,152  :   524,288
  //   qv      @ 2,621,440  :   524,288
  //   lossws  @ 3,145,728  :     4,096  (accum float + ticket int)
  //   partial @ 3,149,824  : 8,388,608  (4*32768*16*4)
  //   hist    @ 11,538,432 : 8,388,608
  char* ws = (char*)d_ws;
  float*   em      = (float*)(ws);
  float*   qmat    = (float*)(ws + 2097152);
  float*   qv      = (float*)(ws + 2621440);
  float*   lossws  = (float*)(ws + 3145728);
  float*   partial = (float*)(ws + 3149824);
  uint8_t* hist    = (uint8_t*)(ws + 11538432);

  hipLaunchKernelGGL(k_gemm_part, dim3(1024), dim3(256), 0, stream, hs, W, partial, lossws);
  hipLaunchKernelGGL(k_em_scan,   dim3(1024), dim3(256), 0, stream, partial, bias, mask, trans, em, qmat, qv, hist);
  hipLaunchKernelGGL(k_tail,      dim3(128),  dim3(512), 0, stream, qv, em, start, endt, hist, labels, mask, trans, qmat, lossws, out, out + 1);
}

// Round 10
// 202.722 us; speedup vs baseline: 1.1022x; 1.1022x over previous
//
#include <hip/hip_runtime.h>
#include <cstdint>

#define Bn 64
#define Ln 512
#define Hn 768
#define Tn 16
#define Cn 8      // chunks over L
#define Sn 64     // chunk length
#define Kn 4      // K-split for GEMM
#define Kc 192    // K-slice per GEMM block (768/4)
#define Mrows (Bn*Ln)   // 32768
#define LOG16 2.7725887222397812f

// ---------------- K_A: partial GEMM, split-K, W-in-LDS + SCALAR reg prefetch --------
// r8/r9 post-mortem: float4 pv[4] (+sr[4]/sj[4]) went to SCRATCH (rule #20 —
// compiler failed SROA across the cc-loop back edge; WRITE_SIZE 85-88MB = 324B/thr
// = pv stored 5x; launch_bounds change was irrelevant, VGPR 44 with spills).
// Fix: NAMED scalars pv0..pv3, inline address math.  Same addresses as lineage
// staging map (f=it*256+tid -> row=32*it+(tid>>3), col=(tid&7)*4) -> identical
// LDS image -> partial/em BIT-IDENTICAL -> tags unchanged.
__global__ __launch_bounds__(256, 4) void k_gemm_part(
    const float* __restrict__ hs, const float* __restrict__ W,
    float* __restrict__ partial, float* __restrict__ lossws) {
  int bx = blockIdx.x;
  int tid = threadIdx.x;
  if (bx == 0 && tid == 0) {               // zero loss accumulator + ticket each iter
    lossws[0] = 0.f;
    ((int*)lossws)[1] = 0;
  }
  int rt = bx >> 2, s = bx & 3;
  int r0 = rt * 128, kb = s * Kc;
  int row = (tid & 63) + ((tid >> 7) << 6);   // waves 0,1 -> rows 0-63; waves 2,3 -> 64-127
  int t0 = ((tid >> 6) & 1) * 8;              // wave-uniform t-half
  __shared__ float alds[128 * 36];            // 18,432 B (stride 36: 0 conflicts measured)
  __shared__ float wlds[16 * 192];            // 12,288 B: W slice, broadcast-read
  float acc[8] = {0.f};
  // stage W slice once (768 float4, 3/thread, 16B runs per t-row)
  for (int idx = tid; idx < 768; idx += 256) {
    int t = idx / 48, jj = idx - t * 48;
    *(float4*)&wlds[t * 192 + jj * 4] = *(const float4*)(W + (size_t)t * Hn + kb + jj * 4);
  }
  // staging slots (lineage map, named): rows rr, rr+32, rr+64, rr+96; col jj4
  int rr = tid >> 3, jj4 = (tid & 7) * 4;
  const float* s0 = hs + (size_t)(r0 + rr)      * Hn + kb + jj4;
  const float* s1 = hs + (size_t)(r0 + rr + 32) * Hn + kb + jj4;
  const float* s2 = hs + (size_t)(r0 + rr + 64) * Hn + kb + jj4;
  const float* s3 = hs + (size_t)(r0 + rr + 96) * Hn + kb + jj4;
  float* d0 = &alds[(rr)      * 36 + jj4];
  float* d1 = &alds[(rr + 32) * 36 + jj4];
  float* d2 = &alds[(rr + 64) * 36 + jj4];
  float* d3 = &alds[(rr + 96) * 36 + jj4];
  float4 pv0 = *(const float4*)(s0);            // chunk 0
  float4 pv1 = *(const float4*)(s1);
  float4 pv2 = *(const float4*)(s2);
  float4 pv3 = *(const float4*)(s3);
#pragma unroll 1
  for (int cc = 0; cc < 6; ++cc) {            // 6 sub-chunks of 32 K-floats
    *(float4*)d0 = pv0;                       // commit prefetched regs to LDS
    *(float4*)d1 = pv1;
    *(float4*)d2 = pv2;
    *(float4*)d3 = pv3;
    __syncthreads();                          // covers W staging at cc=0 too
    if (cc < 5) {                             // issue next chunk's loads under the FMAs
      int off = (cc + 1) * 32;
      pv0 = *(const float4*)(s0 + off);
      pv1 = *(const float4*)(s1 + off);
      pv2 = *(const float4*)(s2 + off);
      pv3 = *(const float4*)(s3 + off);
    }
#pragma unroll
    for (int j = 0; j < 8; ++j) {             // EXACT lineage nest: j asc, xyzw
      float4 a = *(const float4*)&alds[row * 36 + j * 4];
#pragma unroll
      for (int tt = 0; tt < 8; ++tt) {
        float4 wv = *(const float4*)&wlds[(t0 + tt) * 192 + cc * 32 + j * 4];  // broadcast
        acc[tt] = fmaf(a.x, wv.x, fmaf(a.y, wv.y, fmaf(a.z, wv.z, fmaf(a.w, wv.w, acc[tt]))));
      }
    }
    __syncthreads();
  }
  float* dst = partial + ((size_t)s * Mrows + (r0 + row)) * Tn + t0;
  *(float4*)(dst + 0) = make_float4(acc[0], acc[1], acc[2], acc[3]);
  *(float4*)(dst + 4) = make_float4(acc[4], acc[5], acc[6], acc[7]);
}

// ---------------- K_B: reduce+em, then ONE scan per block (r5 form, verbatim) -------
// blocks 0..511: reduce + denom scan (+em write); 512..1023: reduce + Viterbi.
// pbuf broadcast: 1 ds_write + 4 ds_read_b128 per step; serial chains keep exact
// order -> qmat/qv/hist bit-identical -> tags unchanged.
__global__ __launch_bounds__(256) void k_em_scan(
    const float* __restrict__ partial, const float* __restrict__ bias,
    const int* __restrict__ mask, const float* __restrict__ trans,
    float* __restrict__ em, float* __restrict__ qmat,
    float* __restrict__ qv, uint8_t* __restrict__ hist) {
  int half = blockIdx.x >> 9, bc = blockIdx.x & 511;
  int b = bc >> 3, c = bc & 7;
  int tid = threadIdx.x, i = tid >> 4, tp = tid & 15;
  int l0 = c * Sn;
  __shared__ float ems[Sn * Tn];
  __shared__ int msk[Sn];
  __shared__ float pbuf[256];            // per-group broadcast row (16 floats/group)
  __shared__ uint8_t hl[Tn * Sn * Tn];   // 16 KB (used by half 1 only)
  // phase 0: reduce partial -> em (bit-identical order: bias + s0..s3)
#pragma unroll
  for (int g = 0; g < 4; ++g) {
    int rl = (tid >> 4) + g * 16, t = tid & 15;
    int grow = bc * Sn + rl;
    float sum = bias[t];
#pragma unroll
    for (int s = 0; s < Kn; ++s) sum += partial[((size_t)s * Mrows + grow) * Tn + t];
    float mx = sum;
    mx = fmaxf(mx, __shfl_xor(mx, 1));
    mx = fmaxf(mx, __shfl_xor(mx, 2));
    mx = fmaxf(mx, __shfl_xor(mx, 4));
    mx = fmaxf(mx, __shfl_xor(mx, 8));
    float ev = sum - (mx + LOG16);
    ems[rl * Tn + t] = ev;
    if (half == 0) em[(size_t)grow * Tn + t] = ev;
  }
  if (tid < Sn) msk[tid] = mask[b * Ln + l0 + tid];
  __syncthreads();
  int lstart = (c == 0) ? 1 : l0;
  int gb = i << 4;                       // group base in pbuf (64B aligned)
  if (half == 0) {
    // denominator scan (linear space, renorm every 16); dot chain t=0..15 as lineage
    float etr[Tn];
#pragma unroll
    for (int t = 0; t < Tn; ++t) etr[t] = __expf(trans[t * Tn + tp]);
    float p = (tp == i) ? 1.f : 0.f;
    float logs = 0.f;
    for (int l = lstart; l < l0 + Sn; ++l) {
      pbuf[tid] = p;
      __builtin_amdgcn_sched_barrier(0);
      float4 q0 = *(const float4*)&pbuf[gb + 0];
      float4 q1 = *(const float4*)&pbuf[gb + 4];
      float4 q2 = *(const float4*)&pbuf[gb + 8];
      float4 q3 = *(const float4*)&pbuf[gb + 12];
      float cs = __expf(ems[(l - l0) * Tn + tp]);
      float dot = 0.f;
      dot = fmaf(q0.x, etr[0],  dot); dot = fmaf(q0.y, etr[1],  dot);
      dot = fmaf(q0.z, etr[2],  dot); dot = fmaf(q0.w, etr[3],  dot);
      dot = fmaf(q1.x, etr[4],  dot); dot = fmaf(q1.y, etr[5],  dot);
      dot = fmaf(q1.z, etr[6],  dot); dot = fmaf(q1.w, etr[7],  dot);
      dot = fmaf(q2.x, etr[8],  dot); dot = fmaf(q2.y, etr[9],  dot);
      dot = fmaf(q2.z, etr[10], dot); dot = fmaf(q2.w, etr[11], dot);
      dot = fmaf(q3.x, etr[12], dot); dot = fmaf(q3.y, etr[13], dot);
      dot = fmaf(q3.z, etr[14], dot); dot = fmaf(q3.w, etr[15], dot);
      float pn = dot * cs;
      p = msk[l - l0] ? pn : p;
      if ((l & 15) == 15) {
        float m = p;
        m = fmaxf(m, __shfl_xor(m, 1));
        m = fmaxf(m, __shfl_xor(m, 2));
        m = fmaxf(m, __shfl_xor(m, 4));
        m = fmaxf(m, __shfl_xor(m, 8));
        p /= m;
        logs += __logf(m);
      }
    }
    qmat[(((size_t)b * Cn + c) * Tn + i) * Tn + tp] = __logf(p) + logs;
  } else {
    // Viterbi scan (max-plus) + history; serial t=0..15, strict > keeps FIRST max
    float tcol[Tn];
#pragma unroll
    for (int t = 0; t < Tn; ++t) tcol[t] = trans[t * Tn + tp];
    float v = (tp == i) ? 0.f : -1e30f;
    for (int l = lstart; l < l0 + Sn; ++l) {
      pbuf[tid] = v;
      __builtin_amdgcn_sched_barrier(0);
      float4 q0 = *(const float4*)&pbuf[gb + 0];
      float4 q1 = *(const float4*)&pbuf[gb + 4];
      float4 q2 = *(const float4*)&pbuf[gb + 8];
      float4 q3 = *(const float4*)&pbuf[gb + 12];
      float best = -3.0e38f; int arg = 0;
#define VSTEP(val, t) { float cand = (val) + tcol[t]; bool g = cand > best; \
                        arg = g ? (t) : arg; best = g ? cand : best; }
      VSTEP(q0.x, 0)  VSTEP(q0.y, 1)  VSTEP(q0.z, 2)  VSTEP(q0.w, 3)
      VSTEP(q1.x, 4)  VSTEP(q1.y, 5)  VSTEP(q1.z, 6)  VSTEP(q1.w, 7)
      VSTEP(q2.x, 8)  VSTEP(q2.y, 9)  VSTEP(q2.z, 10) VSTEP(q2.w, 11)
      VSTEP(q3.x, 12) VSTEP(q3.y, 13) VSTEP(q3.z, 14) VSTEP(q3.w, 15)
#undef VSTEP
      v = best + ems[(l - l0) * Tn + tp];
      hl[(i * Sn + (l - l0)) * Tn + tp] = (uint8_t)arg;
    }
    qv[(((size_t)b * Cn + c) * Tn + i) * Tn + tp] = v;
    __syncthreads();
    const uint4* s4 = (const uint4*)hl;   // coalesced 16KB dump
    uint4* d4 = (uint4*)(hist + (size_t)bc * (Tn * Sn * Tn));
    for (int k = tid; k < (Tn * Sn * Tn) / 16; k += 256) d4[k] = s4[k];
  }
}

// ---------------- K_C: merged tail — folds read from LDS-staged q-blocks (r8 form) --
__global__ __launch_bounds__(512) void k_tail(
    const float* __restrict__ qv, const float* __restrict__ em,
    const float* __restrict__ start, const float* __restrict__ endt,
    const uint8_t* __restrict__ hist, const int* __restrict__ labels,
    const int* __restrict__ mask, const float* __restrict__ trans,
    const float* __restrict__ qmat, float* __restrict__ lossws,
    float* __restrict__ loss_out, float* __restrict__ tags) {
  int bid = blockIdx.x, tid = threadIdx.x;
  __shared__ float qs[Cn * Tn * Tn];     // 8 KB staged fold matrix
  if (bid >= Bn) {
    // ---- numerator + denominator fold -> llh contribution for b = bid-64 ----
    int b = bid - Bn;
    // issue qmat preload first: 2048 floats = 512 float4, one per thread
    {
      float4 qv4 = *(((const float4*)qmat) + (size_t)b * 512 + tid);
      *(((float4*)qs) + tid) = qv4;
    }
    {
      int l = tid;                         // 512 threads = one l each
      int y = labels[b * Ln + l];
      int m = mask[b * Ln + l];
      float s;
      if (l == 0) s = start[y] + em[((size_t)b * Ln) * Tn + y];
      else s = m ? (trans[labels[b * Ln + l - 1] * Tn + y] + em[((size_t)b * Ln + l) * Tn + y]) : 0.f;
      int msum = m;
      for (int off = 32; off; off >>= 1) {
        s += __shfl_down(s, off);
        msum += __shfl_down(msum, off);
      }
      __shared__ float sw[8]; __shared__ int mw[8];
      __shared__ float snum;
      int wid = tid >> 6, ln = tid & 63;
      if (ln == 0) { sw[wid] = s; mw[wid] = msum; }
      __syncthreads();
      if (tid == 0) {
        float st = 0.f; int mt = 0;
        for (int wv = 0; wv < 8; ++wv) { st += sw[wv]; mt += mw[wv]; }
        snum = st + endt[labels[b * Ln + mt - 1]];
      }
      __syncthreads();                    // qs preload also complete by here
      if (tid < Tn) {                     // 16-lane log-space fold over LDS-staged qmat
        int k = tid;
        float p = start[k] + em[((size_t)b * Ln) * Tn + k];
        for (int c = 0; c < Cn; ++c) {
          float vals[Tn]; float mx = -3.0e38f;
#pragma unroll
          for (int i2 = 0; i2 < Tn; ++i2) {
            float cand = __shfl(p, i2, 16) + qs[c * 256 + i2 * 16 + k];
            vals[i2] = cand;
            mx = fmaxf(mx, cand);
          }
          float sm = 0.f;
#pragma unroll
          for (int i2 = 0; i2 < Tn; ++i2) sm += __expf(vals[i2] - mx);
          p = mx + __logf(sm);
        }
        float x = p + endt[k];
        float mx = x;
        mx = fmaxf(mx, __shfl_xor(mx, 1));
        mx = fmaxf(mx, __shfl_xor(mx, 2));
        mx = fmaxf(mx, __shfl_xor(mx, 4));
        mx = fmaxf(mx, __shfl_xor(mx, 8));
        float e = __expf(x - mx);
        e += __shfl_xor(e, 1);
        e += __shfl_xor(e, 2);
        e += __shfl_xor(e, 4);
        e += __shfl_xor(e, 8);
        float denom = mx + __logf(e);
        if (k == 0) {
          atomicAdd(&lossws[0], snum - denom);
          __threadfence();
          int ticket = atomicAdd((int*)lossws + 1, 1);
          if (ticket == Bn - 1) {         // last numer block finalizes loss
            __threadfence();
            float total = atomicAdd(&lossws[0], 0.f);
            loss_out[0] = -total * (1.0f / Bn);
          }
        }
      }
    }
    return;
  }
  // ---- Viterbi fold + parallel backtrack for b = bid ----
  int b = bid;
  __shared__ int Bs[Cn][Tn];
  __shared__ int bnd[Cn + 1];
  {
    float4 qv4 = *(((const float4*)qv) + (size_t)b * 512 + tid);  // stage qv block
    *(((float4*)qs) + tid) = qv4;
  }
  __syncthreads();
  if (tid < Tn) {
    int k = tid;
    float p = start[k] + em[((size_t)b * Ln) * Tn + k];
    for (int c = 0; c < Cn; ++c) {
      float best = -3.0e38f; int arg = 0;
#pragma unroll
      for (int i2 = 0; i2 < Tn; ++i2) {
        float cand = __shfl(p, i2, 16) + qs[c * 256 + i2 * 16 + k];
        bool g = cand > best;
        arg = g ? i2 : arg;
        best = g ? cand : best;
      }
      Bs[c][k] = arg;
      p = best;
    }
    float x = p + endt[k]; int idx = k;   // first-max argmax over k
#pragma unroll
    for (int d = 1; d < 16; d <<= 1) {
      float xo = __shfl_xor(x, d);
      int io = __shfl_xor(idx, d);
      bool take = (xo > x) || (xo == x && io < idx);
      x = take ? xo : x;
      idx = take ? io : idx;
    }
    if (k == 0) bnd[Cn] = idx;
  }
  __syncthreads();
  if (tid == 0) {
    int t = bnd[Cn];
    for (int c = Cn - 1; c >= 0; --c) { t = Bs[c][t]; bnd[c] = t; }
  }
  __syncthreads();
  int w = tid >> 6, lane = tid & 63;      // wave w backtracks chunk w
  int istar = bnd[w];
  int cur = bnd[w + 1];
  int l0 = w * Sn;
  const uint4* hp = (const uint4*)(hist + ((size_t)(b * Cn + w) * Tn + istar) * (Sn * Tn));
  uint4 hh = hp[lane];
  float mytag = (lane == 63) ? (float)cur : 0.f;
  for (int l = l0 + 63; l >= l0 + 1; --l) {
    int sl = l - l0;
    unsigned w0 = __shfl((int)hh.x, sl);
    unsigned w1 = __shfl((int)hh.y, sl);
    unsigned w2 = __shfl((int)hh.z, sl);
    unsigned w3 = __shfl((int)hh.w, sl);
    unsigned word = (cur < 8) ? ((cur < 4) ? w0 : w1) : ((cur < 12) ? w2 : w3);
    cur = (int)((word >> ((cur & 3) * 8)) & 0xff);
    if (lane == sl - 1) mytag = (float)cur;
  }
  tags[(size_t)b * Ln + l0 + lane] = mytag;
}

extern "C" void kernel_launch(void* const* d_in, const int* in_sizes, int n_in,
                              void* d_out, int out_size, void* d_ws, size_t ws_size,
                              hipStream_t stream) {
  const float* hs     = (const float*)d_in[0];
  const int*   mask   = (const int*)d_in[1];
  const int*   labels = (const int*)d_in[2];
  const float* W      = (const float*)d_in[3];
  const float* bias   = (const float*)d_in[4];
  const float* start  = (const float*)d_in[5];
  const float* endt   = (const float*)d_in[6];
  const float* trans  = (const float*)d_in[7];
  float* out = (float*)d_out;

  // Workspace (~19.9 MB, NO aliasing — partial & hist are concurrently live in K_B):
  //   em      @ 0          : 2,097,152
  //   qmat    @ 2,097,152  :   524,288
  //   qv      @ 2,621,440  :   524,288
  //   lossws  @ 3,145,728  :     4,096  (accum float + ticket int)
  //   partial @ 3,149,824  : 8,388,608  (4*32768*16*4)
  //   hist    @ 11,538,432 : 8,388,608
  char* ws = (char*)d_ws;
  float*   em      = (float*)(ws);
  float*   qmat    = (float*)(ws + 2097152);
  float*   qv      = (float*)(ws + 2621440);
  float*   lossws  = (float*)(ws + 3145728);
  float*   partial = (float*)(ws + 3149824);
  uint8_t* hist    = (uint8_t*)(ws + 11538432);

  hipLaunchKernelGGL(k_gemm_part, dim3(1024), dim3(256), 0, stream, hs, W, partial, lossws);
  hipLaunchKernelGGL(k_em_scan,   dim3(1024), dim3(256), 0, stream, partial, bias, mask, trans, em, qmat, qv, hist);
  hipLaunchKernelGGL(k_tail,      dim3(128),  dim3(512), 0, stream, qv, em, start, endt, hist, labels, mask, trans, qmat, lossws, out, out + 1);
}